// Round 1
// baseline (1262.500 us; speedup 1.0000x reference)
//
#include <hip/hip_runtime.h>
#include <stdint.h>

#define B_SIZE  524288
#define NT      20        // 20 output tiles of 16 cols: 16 gate tiles + 4 head tiles
#define GATE_T  16

typedef float f32x4  __attribute__((ext_vector_type(4)));
typedef short bf16x8 __attribute__((ext_vector_type(8)));

__device__ __forceinline__ uint16_t f2bf(float f) {
    uint32_t u = __float_as_uint(f);
    u += 0x7fffu + ((u >> 16) & 1u);   // round-to-nearest-even
    return (uint16_t)(u >> 16);
}

__device__ __forceinline__ float sigm(float v) {
    return __builtin_amdgcn_rcpf(1.0f + __expf(-v));
}
__device__ __forceinline__ float tanh_f(float v) {
    // tanh(x) = 1 - 2/(e^{2x}+1); exp overflow -> inf -> rcp=0 -> 1 (correct limit)
    return 1.0f - 2.0f * __builtin_amdgcn_rcpf(__expf(2.0f * v) + 1.0f);
}

// Pack weights into MFMA B-fragment order:
// chunk idx = t*256 + kb*64 + lane ; chunk holds 8 bf16 = W_all[t*16+(lane&15)][kb*32+(lane>>4)*8 + 0..7]
// W_all rows 0..255 = [W_ih | W_hh] (gate order i,f,g,o), rows 256..319 = W_o.
__global__ __launch_bounds__(256) void prep_weights(
    const float* __restrict__ W_ih, const float* __restrict__ W_hh,
    const float* __restrict__ b_ih, const float* __restrict__ b_hh,
    const float* __restrict__ W_o,  const float* __restrict__ b_o,
    uint16_t* __restrict__ wfrag, float* __restrict__ bias_all)
{
    int idx = blockIdx.x * 256 + threadIdx.x;
    if (idx < NT * 4 * 64) {
        int lane = idx & 63;
        int kb   = (idx >> 6) & 3;
        int t    = idx >> 8;
        int n    = t * 16 + (lane & 15);
        int k0   = kb * 32 + (lane >> 4) * 8;
        float v[8];
        if (n < 256) {
            if (k0 < 64) {
                #pragma unroll
                for (int j = 0; j < 8; ++j) v[j] = W_ih[n * 64 + k0 + j];
            } else {
                #pragma unroll
                for (int j = 0; j < 8; ++j) v[j] = W_hh[n * 64 + (k0 - 64) + j];
            }
        } else {
            #pragma unroll
            for (int j = 0; j < 8; ++j) v[j] = W_o[(n - 256) * 128 + k0 + j];
        }
        uint16_t* dst = wfrag + (size_t)idx * 8;
        #pragma unroll
        for (int j = 0; j < 8; ++j) dst[j] = f2bf(v[j]);
    }
    if (idx < NT * 16) {
        bias_all[idx] = (idx < 256) ? (b_ih[idx] + b_hh[idx]) : b_o[idx - 256];
    }
}

__global__ __launch_bounds__(256, 2) void lstm_fused(
    const float* __restrict__ x, const float* __restrict__ h0,
    const float* __restrict__ c0,
    const uint16_t* __restrict__ wfrag, const float* __restrict__ bias_all,
    float* __restrict__ out)
{
    __shared__ __align__(16) uint16_t lds_w[GATE_T * 4 * 64 * 8]; // 64 KB: gate-tile weights
    __shared__ float lds_bias[NT * 16];

    const int tid = threadIdx.x;
    {
        const uint4* src = (const uint4*)wfrag;
        uint4* dst = (uint4*)lds_w;
        for (int i = tid; i < GATE_T * 4 * 64; i += 256) dst[i] = src[i];
        for (int i = tid; i < NT * 16; i += 256) lds_bias[i] = bias_all[i];
    }
    __syncthreads();

    const int wave = tid >> 6;
    const int lane = tid & 63;
    const int lrow = lane & 15;   // A row / B col within tile; also C/D col
    const int quad = lane >> 4;   // 0..3

    float biasr[NT];
    #pragma unroll
    for (int t = 0; t < NT; ++t) biasr[t] = lds_bias[t * 16 + lrow];

    float* out_logp = out;
    float* out_h = out + (size_t)B_SIZE * 64;
    float* out_c = out + (size_t)2 * B_SIZE * 64;

    const int nwt = B_SIZE / 16;        // 32768 row-tiles
    const int stride = gridDim.x * 4;   // total waves

    for (int wt = blockIdx.x * 4 + wave; wt < nwt; wt += stride) {
        const int R = wt * 16;

        // ---- A fragments: combined[row][k], row=R+lrow, k = kb*32 + quad*8 + j ----
        bf16x8 afrag[4];
        {
            const float* xr = x  + (size_t)(R + lrow) * 64 + quad * 8;
            const float* hr = h0 + (size_t)(R + lrow) * 64 + quad * 8;
            f32x4 x0 = *(const f32x4*)(xr);
            f32x4 x1 = *(const f32x4*)(xr + 4);
            f32x4 x2 = *(const f32x4*)(xr + 32);
            f32x4 x3 = *(const f32x4*)(xr + 36);
            f32x4 ha = *(const f32x4*)(hr);
            f32x4 hb = *(const f32x4*)(hr + 4);
            f32x4 hc = *(const f32x4*)(hr + 32);
            f32x4 hd = *(const f32x4*)(hr + 36);
            #pragma unroll
            for (int j = 0; j < 4; ++j) {
                afrag[0][j]     = (short)f2bf(x0[j]);
                afrag[0][4 + j] = (short)f2bf(x1[j]);
                afrag[1][j]     = (short)f2bf(x2[j]);
                afrag[1][4 + j] = (short)f2bf(x3[j]);
                afrag[2][j]     = (short)f2bf(ha[j]);
                afrag[2][4 + j] = (short)f2bf(hb[j]);
                afrag[3][j]     = (short)f2bf(hc[j]);
                afrag[3][4 + j] = (short)f2bf(hd[j]);
            }
        }

        // ---- c0 at each accumulator position: row=R+quad*4+r, col=u*16+lrow ----
        float cv[4][4];
        #pragma unroll
        for (int u = 0; u < 4; ++u)
            #pragma unroll
            for (int r = 0; r < 4; ++r)
                cv[u][r] = c0[(size_t)(R + quad * 4 + r) * 64 + u * 16 + lrow];

        // ---- MFMA: 20 tiles x 4 kblocks, acc seeded with bias (bias depends on col only) ----
        f32x4 acc[NT];
        #pragma unroll
        for (int t = 0; t < NT; ++t) {
            f32x4 b4 = {biasr[t], biasr[t], biasr[t], biasr[t]};
            acc[t] = b4;
        }

        #pragma unroll
        for (int t = 0; t < GATE_T; ++t) {
            #pragma unroll
            for (int kb = 0; kb < 4; ++kb) {
                bf16x8 bfrag = *(const bf16x8*)(lds_w + ((t * 4 + kb) * 64 + lane) * 8);
                acc[t] = __builtin_amdgcn_mfma_f32_16x16x32_bf16(afrag[kb], bfrag, acc[t], 0, 0, 0);
            }
        }
        #pragma unroll
        for (int t = GATE_T; t < NT; ++t) {   // head tiles: weights from global (L1-resident 16 KB)
            #pragma unroll
            for (int kb = 0; kb < 4; ++kb) {
                bf16x8 bfrag = *(const bf16x8*)(wfrag + ((size_t)(t * 4 + kb) * 64 + lane) * 8);
                acc[t] = __builtin_amdgcn_mfma_f32_16x16x32_bf16(afrag[kb], bfrag, acc[t], 0, 0, 0);
            }
        }

        // ---- gate epilogue: i=tiles 0..3, f=4..7, g=8..11, o=12..15 (same lane/reg => same row,col) ----
        #pragma unroll
        for (int u = 0; u < 4; ++u) {
            #pragma unroll
            for (int r = 0; r < 4; ++r) {
                float ig = sigm(acc[u][r]);
                float fg = sigm(acc[4 + u][r]);
                float gg = tanh_f(acc[8 + u][r]);
                float og = sigm(acc[12 + u][r]);
                float cn = fg * cv[u][r] + ig * gg;
                float hn = og * tanh_f(cn);
                size_t off = (size_t)(R + quad * 4 + r) * 64 + u * 16 + lrow;
                out_c[off] = cn;
                out_h[off] = hn;
            }
        }

        // ---- head epilogue: log_softmax over the 64 logits of each row ----
        // row r data: 16 lanes of this quad, reg=r, across tiles 16..19
        #pragma unroll
        for (int r = 0; r < 4; ++r) {
            float v0 = acc[16][r], v1 = acc[17][r], v2 = acc[18][r], v3 = acc[19][r];
            float m = fmaxf(fmaxf(v0, v1), fmaxf(v2, v3));
            #pragma unroll
            for (int s = 1; s < 16; s <<= 1) m = fmaxf(m, __shfl_xor(m, s, 16));
            float ssum = __expf(v0 - m) + __expf(v1 - m) + __expf(v2 - m) + __expf(v3 - m);
            #pragma unroll
            for (int s = 1; s < 16; s <<= 1) ssum += __shfl_xor(ssum, s, 16);
            float lse = m + __logf(ssum);
            size_t off = (size_t)(R + quad * 4 + r) * 64 + lrow;
            out_logp[off]      = v0 - lse;
            out_logp[off + 16] = v1 - lse;
            out_logp[off + 32] = v2 - lse;
            out_logp[off + 48] = v3 - lse;
        }
    }
}

extern "C" void kernel_launch(void* const* d_in, const int* in_sizes, int n_in,
                              void* d_out, int out_size, void* d_ws, size_t ws_size,
                              hipStream_t stream)
{
    const float* x    = (const float*)d_in[0];
    const float* h0   = (const float*)d_in[1];
    const float* c0   = (const float*)d_in[2];
    const float* W_ih = (const float*)d_in[3];
    const float* W_hh = (const float*)d_in[4];
    const float* b_ih = (const float*)d_in[5];
    const float* b_hh = (const float*)d_in[6];
    const float* W_o  = (const float*)d_in[7];
    const float* b_o  = (const float*)d_in[8];

    uint16_t* wfrag = (uint16_t*)d_ws;
    float* bias_all = (float*)((char*)d_ws + (size_t)NT * 4 * 64 * 8 * sizeof(uint16_t));

    prep_weights<<<20, 256, 0, stream>>>(W_ih, W_hh, b_ih, b_hh, W_o, b_o, wfrag, bias_all);
    lstm_fused<<<512, 256, 0, stream>>>(x, h0, c0, wfrag, bias_all, (float*)d_out);
}

// Round 2
// 727.516 us; speedup vs baseline: 1.7354x; 1.7354x over previous
//
#include <hip/hip_runtime.h>
#include <stdint.h>

#define B_SIZE  524288
#define NT      20        // 20 output tiles of 16 features: 16 gate tiles + 4 head tiles
#define GATE_T  16

typedef float f32x4  __attribute__((ext_vector_type(4)));
typedef short bf16x8 __attribute__((ext_vector_type(8)));

__device__ __forceinline__ uint16_t f2bf(float f) {
    uint32_t u = __float_as_uint(f);
    u += 0x7fffu + ((u >> 16) & 1u);   // round-to-nearest-even
    return (uint16_t)(u >> 16);
}

__device__ __forceinline__ float sigm(float v) {
    return __builtin_amdgcn_rcpf(1.0f + __expf(-v));
}
__device__ __forceinline__ float tanh_f(float v) {
    // tanh(x) = 1 - 2/(e^{2x}+1); exp overflow -> inf -> rcp=0 -> 1 (correct limit)
    return 1.0f - 2.0f * __builtin_amdgcn_rcpf(__expf(2.0f * v) + 1.0f);
}

// Pack weights into MFMA fragment order (used as A operand: A[m=lane&15][k=(lane>>4)*8+j]):
// chunk idx = t*256 + kb*64 + lane ; chunk holds 8 bf16 = W_all[t*16+(lane&15)][kb*32+(lane>>4)*8 + 0..7]
// W_all rows 0..255 = [W_ih | W_hh] (gate order i,f,g,o), rows 256..319 = W_o.
__global__ __launch_bounds__(256) void prep_weights(
    const float* __restrict__ W_ih, const float* __restrict__ W_hh,
    const float* __restrict__ b_ih, const float* __restrict__ b_hh,
    const float* __restrict__ W_o,  const float* __restrict__ b_o,
    uint16_t* __restrict__ wfrag, float* __restrict__ bias_all)
{
    int idx = blockIdx.x * 256 + threadIdx.x;
    if (idx < NT * 4 * 64) {
        int lane = idx & 63;
        int kb   = (idx >> 6) & 3;
        int t    = idx >> 8;
        int n    = t * 16 + (lane & 15);
        int k0   = kb * 32 + (lane >> 4) * 8;
        float v[8];
        if (n < 256) {
            if (k0 < 64) {
                #pragma unroll
                for (int j = 0; j < 8; ++j) v[j] = W_ih[n * 64 + k0 + j];
            } else {
                #pragma unroll
                for (int j = 0; j < 8; ++j) v[j] = W_hh[n * 64 + (k0 - 64) + j];
            }
        } else {
            #pragma unroll
            for (int j = 0; j < 8; ++j) v[j] = W_o[(n - 256) * 128 + k0 + j];
        }
        uint16_t* dst = wfrag + (size_t)idx * 8;
        #pragma unroll
        for (int j = 0; j < 8; ++j) dst[j] = f2bf(v[j]);
    }
    if (idx < NT * 16) {
        bias_all[idx] = (idx < 256) ? (b_ih[idx] + b_hh[idx]) : b_o[idx - 256];
    }
}

__global__ __launch_bounds__(1024) void lstm_fused(
    const float* __restrict__ x, const float* __restrict__ h0,
    const float* __restrict__ c0,
    const uint16_t* __restrict__ wfrag, const float* __restrict__ bias_all,
    float* __restrict__ out)
{
    __shared__ __align__(16) uint16_t lds_w[NT * 4 * 64 * 8]; // 81920 B: ALL weight tiles
    __shared__ float lds_bias[NT * 16];                        // 1280 B

    const int tid = threadIdx.x;
    {
        const uint4* src = (const uint4*)wfrag;
        uint4* dst = (uint4*)lds_w;
        #pragma unroll
        for (int i = 0; i < 5; ++i) dst[tid + i * 1024] = src[tid + i * 1024];
        if (tid < NT * 16) lds_bias[tid] = bias_all[tid];
    }
    __syncthreads();

    const int wave = tid >> 6;
    const int lane = tid & 63;
    const int b    = lane & 15;   // C/D col = batch row within tile
    const int q    = lane >> 4;   // 0..3

    float* out_logp = out;
    float* out_h = out + (size_t)B_SIZE * 64;
    float* out_c = out + (size_t)2 * B_SIZE * 64;

    const int nwt = B_SIZE / 16;
    const int stride = gridDim.x * 16;

    for (int wt = blockIdx.x * 16 + wave; wt < nwt; wt += stride) {
        const int R = wt * 16;

        // ---- B fragments from x,h: lane holds combined[R+b][kb*32 + q*8 + j] ----
        bf16x8 bfr[4];
        {
            const float* xr = x  + (size_t)(R + b) * 64 + q * 8;
            const float* hr = h0 + (size_t)(R + b) * 64 + q * 8;
            f32x4 x0 = __builtin_nontemporal_load((const f32x4*)(xr));
            f32x4 x1 = __builtin_nontemporal_load((const f32x4*)(xr + 4));
            f32x4 x2 = __builtin_nontemporal_load((const f32x4*)(xr + 32));
            f32x4 x3 = __builtin_nontemporal_load((const f32x4*)(xr + 36));
            f32x4 ha = __builtin_nontemporal_load((const f32x4*)(hr));
            f32x4 hb = __builtin_nontemporal_load((const f32x4*)(hr + 4));
            f32x4 hc = __builtin_nontemporal_load((const f32x4*)(hr + 32));
            f32x4 hd = __builtin_nontemporal_load((const f32x4*)(hr + 36));
            #pragma unroll
            for (int j = 0; j < 4; ++j) {
                bfr[0][j]     = (short)f2bf(x0[j]);
                bfr[0][4 + j] = (short)f2bf(x1[j]);
                bfr[1][j]     = (short)f2bf(x2[j]);
                bfr[1][4 + j] = (short)f2bf(x3[j]);
                bfr[2][j]     = (short)f2bf(ha[j]);
                bfr[2][4 + j] = (short)f2bf(hb[j]);
                bfr[3][j]     = (short)f2bf(hc[j]);
                bfr[3][4 + j] = (short)f2bf(hd[j]);
            }
        }

        // opaque zero (SGPR) — prevents LICM from hoisting the 20 bias f32x4 loads
        int zz; asm volatile("s_mov_b32 %0, 0" : "=s"(zz));

        // ---- acc seeded with bias: acc[t][r] = bias[t*16 + q*4 + r] ----
        f32x4 acc[NT];
        #pragma unroll
        for (int t = 0; t < NT; ++t)
            acc[t] = *(const f32x4*)(lds_bias + t * 16 + q * 4 + zz);

        // ---- MFMA: weights as A (from LDS), x/h as B; 20 tiles x 4 kblocks ----
        #pragma unroll
        for (int kb = 0; kb < 4; ++kb) {
            #pragma unroll
            for (int t = 0; t < NT; ++t) {
                bf16x8 wf = *(const bf16x8*)(lds_w + ((t * 4 + kb) * 64 + lane) * 8);
                acc[t] = __builtin_amdgcn_mfma_f32_16x16x32_bf16(wf, bfr[kb], acc[t], 0, 0, 0);
            }
        }

        // ---- gate epilogue: lane holds features u*16+q*4+{0..3} of batch R+b ----
        const float* cr = c0 + (size_t)(R + b) * 64;
        #pragma unroll
        for (int u = 0; u < 4; ++u) {
            f32x4 cv = __builtin_nontemporal_load((const f32x4*)(cr + u * 16 + q * 4));
            f32x4 cn, hn;
            #pragma unroll
            for (int r = 0; r < 4; ++r) {
                float ig = sigm(acc[u][r]);
                float fg = sigm(acc[4 + u][r]);
                float gg = tanh_f(acc[8 + u][r]);
                float og = sigm(acc[12 + u][r]);
                float c1 = fg * cv[r] + ig * gg;
                cn[r] = c1;
                hn[r] = og * tanh_f(c1);
            }
            size_t off = (size_t)(R + b) * 64 + u * 16 + q * 4;
            __builtin_nontemporal_store(cn, (f32x4*)(out_c + off));
            __builtin_nontemporal_store(hn, (f32x4*)(out_h + off));
        }

        // ---- head: logits in acc[16..19]; softmax over 64 = 16 in-lane + quads ----
        float m = acc[16][0];
        #pragma unroll
        for (int u = 0; u < 4; ++u)
            #pragma unroll
            for (int r = 0; r < 4; ++r) m = fmaxf(m, acc[16 + u][r]);
        m = fmaxf(m, __shfl_xor(m, 16));
        m = fmaxf(m, __shfl_xor(m, 32));
        float s = 0.0f;
        #pragma unroll
        for (int u = 0; u < 4; ++u)
            #pragma unroll
            for (int r = 0; r < 4; ++r) s += __expf(acc[16 + u][r] - m);
        s += __shfl_xor(s, 16);
        s += __shfl_xor(s, 32);
        float lse = m + __logf(s);
        #pragma unroll
        for (int u = 0; u < 4; ++u) {
            f32x4 lp;
            #pragma unroll
            for (int r = 0; r < 4; ++r) lp[r] = acc[16 + u][r] - lse;
            __builtin_nontemporal_store(lp, (f32x4*)(out_logp + (size_t)(R + b) * 64 + u * 16 + q * 4));
        }
    }
}

extern "C" void kernel_launch(void* const* d_in, const int* in_sizes, int n_in,
                              void* d_out, int out_size, void* d_ws, size_t ws_size,
                              hipStream_t stream)
{
    const float* x    = (const float*)d_in[0];
    const float* h0   = (const float*)d_in[1];
    const float* c0   = (const float*)d_in[2];
    const float* W_ih = (const float*)d_in[3];
    const float* W_hh = (const float*)d_in[4];
    const float* b_ih = (const float*)d_in[5];
    const float* b_hh = (const float*)d_in[6];
    const float* W_o  = (const float*)d_in[7];
    const float* b_o  = (const float*)d_in[8];

    uint16_t* wfrag = (uint16_t*)d_ws;
    float* bias_all = (float*)((char*)d_ws + (size_t)NT * 4 * 64 * 8 * sizeof(uint16_t));

    prep_weights<<<20, 256, 0, stream>>>(W_ih, W_hh, b_ih, b_hh, W_o, b_o, wfrag, bias_all);
    lstm_fused<<<256, 1024, 0, stream>>>(x, h0, c0, wfrag, bias_all, (float*)d_out);
}